// Round 1
// baseline (1338.944 us; speedup 1.0000x reference)
//
#include <hip/hip_runtime.h>
#include <math.h>

#define BIG_NEG  (-1.0e6f)
#define N_NODES  100
#define M_DIM    128
#define KDIM     256      // NF + HNF
#define G4       512      // 4*M
#define MEM_PAD  130      // padded LDS row stride (2-way bank alias = free)

// ws layout (floats):
#define WS_WEMBT 0        // [256][128]  W_emb transposed
#define WS_WCATT 32768    // [256][512]  [W_ih | W_hh] transposed
#define WS_BIAS  163840   // [512]       b_ih + b_hh

__device__ __forceinline__ float sigm(float x) { return 1.0f / (1.0f + __expf(-x)); }

extern "C" __global__ void prep_kernel(const float* __restrict__ W_emb,
                                       const float* __restrict__ W_ih,
                                       const float* __restrict__ b_ih,
                                       const float* __restrict__ W_hh,
                                       const float* __restrict__ b_hh,
                                       float* __restrict__ ws) {
    int tid = blockIdx.x * blockDim.x + threadIdx.x;
    int nth = gridDim.x * blockDim.x;
    float* WembT = ws + WS_WEMBT;
    float* WcatT = ws + WS_WCATT;
    float* biasc = ws + WS_BIAS;
    for (int i = tid; i < 256 * 128; i += nth) {
        int k = i >> 7, m = i & 127;
        WembT[i] = W_emb[m * 256 + k];
    }
    for (int i = tid; i < 256 * 512; i += nth) {
        int k = i >> 9, g = i & 511;
        WcatT[i] = (k < 128) ? W_ih[g * 128 + k] : W_hh[g * 128 + (k - 128)];
    }
    for (int i = tid; i < 512; i += nth) biasc[i] = b_ih[i] + b_hh[i];
}

extern "C" __global__ __launch_bounds__(512, 1)
void set2vec_main(const float* __restrict__ hidden,
                  const float* __restrict__ input,
                  const float* __restrict__ b_emb,
                  const unsigned char* __restrict__ mask_bytes,
                  const int* __restrict__ Tptr,
                  const float* __restrict__ ws,
                  float* __restrict__ out) {
    __shared__ float mem[2][N_NODES][MEM_PAD];   // 104000 B
    __shared__ float xtile[16][KDIM];            // 16384 B (embed staging)
    __shared__ float xcat2[2][KDIM];             // [lstm_in | h]
    __shared__ float gbuf[2][G4];
    __shared__ float cbuf[2][M_DIM];
    __shared__ float ebuf[2][N_NODES];
    __shared__ float abuf[2][N_NODES];
    __shared__ int   mask_is_u8;

    const int tid = threadIdx.x;
    const int b0  = blockIdx.x * 2;
    const float* WembT = ws + WS_WEMBT;
    const float* WcatT = ws + WS_WCATT;
    const float* biasc = ws + WS_BIAS;

    // --- sniff node_mask dtype: int32 0/1 has zero bytes at i%4!=0 ---
    if (tid == 0) {
        int nz = 0;
        for (int i = 0; i < 256; ++i)
            if ((i & 3) && mask_bytes[i]) nz = 1;
        mask_is_u8 = nz;
    }

    // --- fused embed: mem[bb][n][m] = cat(hidden,input) @ W_emb^T + b_emb ---
    for (int t0 = 0; t0 < 2 * N_NODES; t0 += 16) {
        int nrows = (2 * N_NODES - t0 < 16) ? (2 * N_NODES - t0) : 16;
        for (int i = tid; i < nrows * KDIM; i += 512) {
            int rr = i >> 8, k = i & 255;
            int row = t0 + rr;
            int bb = row >= N_NODES;
            int n  = row - bb * N_NODES;
            long base = ((long)(b0 + bb) * N_NODES + n) * 128;
            xtile[rr][k] = (k < 128) ? hidden[base + k] : input[base + (k - 128)];
        }
        __syncthreads();
        {
            int rr = tid >> 5;            // 0..15
            int m0 = (tid & 31) * 4;      // 0..124
            if (rr < nrows) {
                float4 acc = *(const float4*)(b_emb + m0);
                #pragma unroll 4
                for (int k = 0; k < KDIM; ++k) {
                    float xv = xtile[rr][k];
                    float4 w = *(const float4*)(WembT + k * 128 + m0);
                    acc.x += xv * w.x; acc.y += xv * w.y;
                    acc.z += xv * w.z; acc.w += xv * w.w;
                }
                int row = t0 + rr;
                int bb = row >= N_NODES;
                int n  = row - bb * N_NODES;
                mem[bb][n][m0 + 0] = acc.x;
                mem[bb][n][m0 + 1] = acc.y;
                mem[bb][n][m0 + 2] = acc.z;
                mem[bb][n][m0 + 3] = acc.w;
            }
        }
        __syncthreads();
    }

    // --- init LSTM state ---
    for (int i = tid; i < 2 * KDIM; i += 512) ((float*)xcat2)[i] = 0.0f;
    for (int i = tid; i < 2 * M_DIM; i += 512) ((float*)cbuf)[i] = 0.0f;
    __syncthreads();

    const int T = Tptr[0];   // first 4 bytes work for i32 or i64-LE scalar

    for (int step = 0; step < T; ++step) {
        // --- gates: g = tid, both batch elems share the weight read ---
        {
            int g = tid;
            float a0 = biasc[g];
            float a1 = a0;
            #pragma unroll 8
            for (int k = 0; k < KDIM; ++k) {
                float w = WcatT[k * 512 + g];
                a0 += w * xcat2[0][k];
                a1 += w * xcat2[1][k];
            }
            gbuf[0][g] = a0;
            gbuf[1][g] = a1;
        }
        __syncthreads();
        // --- LSTM pointwise (i,f,g,o order) ---
        if (tid < 256) {
            int bb = tid >> 7, m = tid & 127;
            float gi = gbuf[bb][m];
            float gf = gbuf[bb][128 + m];
            float gg = gbuf[bb][256 + m];
            float go = gbuf[bb][384 + m];
            float c  = cbuf[bb][m];
            c = sigm(gf) * c + sigm(gi) * tanhf(gg);
            float q = sigm(go) * tanhf(c);
            cbuf[bb][m] = c;
            xcat2[bb][128 + m] = q;     // h
        }
        __syncthreads();
        // --- energies ---
        if (tid < 2 * N_NODES) {
            int bb = tid >= N_NODES;
            int n  = tid - bb * N_NODES;
            float e = 0.0f;
            #pragma unroll 4
            for (int m = 0; m < M_DIM; ++m)
                e += xcat2[bb][128 + m] * mem[bb][n][m];
            long mrow = (long)(b0 + bb) * N_NODES + n;
            int valid = mask_is_u8 ? (mask_bytes[mrow] != 0)
                                   : (((const int*)mask_bytes)[mrow] != 0);
            ebuf[bb][n] = e + (valid ? 0.0f : BIG_NEG);
        }
        __syncthreads();
        // --- softmax over n (wave 0 -> b0, wave 1 -> b1) ---
        if (tid < 128) {
            int bb = tid >> 6, l = tid & 63;
            float v0 = ebuf[bb][l];
            float v1 = (l + 64 < N_NODES) ? ebuf[bb][l + 64] : -INFINITY;
            float mx = fmaxf(v0, v1);
            for (int off = 32; off; off >>= 1) mx = fmaxf(mx, __shfl_xor(mx, off, 64));
            float p0 = __expf(v0 - mx);
            float p1 = (l + 64 < N_NODES) ? __expf(v1 - mx) : 0.0f;
            float s = p0 + p1;
            for (int off = 32; off; off >>= 1) s += __shfl_xor(s, off, 64);
            float inv = 1.0f / s;
            abuf[bb][l] = p0 * inv;
            if (l + 64 < N_NODES) abuf[bb][l + 64] = p1 * inv;
        }
        __syncthreads();
        // --- read ---
        if (tid < 256) {
            int bb = tid >> 7, m = tid & 127;
            float r = 0.0f;
            #pragma unroll 4
            for (int n = 0; n < N_NODES; ++n)
                r += abuf[bb][n] * mem[bb][n][m];
            xcat2[bb][m] = r;           // lstm_in for next step
        }
        __syncthreads();
    }

    // --- output: [q | read] per batch element ---
    {
        int bb = tid >> 8, j = tid & 255;
        float v = (j < 128) ? xcat2[bb][128 + j] : xcat2[bb][j - 128];
        out[(long)(b0 + bb) * 256 + j] = v;
    }
}

extern "C" void kernel_launch(void* const* d_in, const int* in_sizes, int n_in,
                              void* d_out, int out_size, void* d_ws, size_t ws_size,
                              hipStream_t stream) {
    const float* hidden = (const float*)d_in[0];
    const float* input  = (const float*)d_in[1];
    const float* W_emb  = (const float*)d_in[2];
    const float* b_emb  = (const float*)d_in[3];
    const float* W_ih   = (const float*)d_in[4];
    const float* b_ih   = (const float*)d_in[5];
    const float* W_hh   = (const float*)d_in[6];
    const float* b_hh   = (const float*)d_in[7];
    const unsigned char* mask = (const unsigned char*)d_in[8];
    const int*  Tptr    = (const int*)d_in[9];
    float* ws  = (float*)d_ws;
    float* out = (float*)d_out;

    hipLaunchKernelGGL(prep_kernel, dim3(128), dim3(256), 0, stream,
                       W_emb, W_ih, b_ih, W_hh, b_hh, ws);
    hipLaunchKernelGGL(set2vec_main, dim3(1024), dim3(512), 0, stream,
                       hidden, input, b_emb, mask, Tptr, ws, out);
}

// Round 2
// 1068.216 us; speedup vs baseline: 1.2534x; 1.2534x over previous
//
#include <hip/hip_runtime.h>
#include <math.h>

#define BIG_NEG  (-1.0e6f)
#define NN   100
#define MD   128
#define KD   256
#define G4   512
#define MPAD 130

// ws layout:
//   floats [0, 32768)      : WembT [256][128] (W_emb transposed, fp32)
//   uints  [32768, 98304)  : WcatT2 [128][512] (bf16 pair: k=2kp low half, 2kp+1 high half)
//   floats [98304, 98816)  : biasc = b_ih + b_hh
#define WS_WEMBT 0
#define WS_WCAT2 32768
#define WS_BIAS  98304

__device__ __forceinline__ unsigned short f2bf(float x) {
    unsigned u = __float_as_uint(x);
    unsigned r = (u + 0x7fffu + ((u >> 16) & 1u)) >> 16;   // RNE
    return (unsigned short)r;
}
__device__ __forceinline__ float sigm(float x) { return 1.0f / (1.0f + __expf(-x)); }

extern "C" __global__ void prep_kernel(const float* __restrict__ W_emb,
                                       const float* __restrict__ W_ih,
                                       const float* __restrict__ b_ih,
                                       const float* __restrict__ W_hh,
                                       const float* __restrict__ b_hh,
                                       float* __restrict__ ws) {
    int tid = blockIdx.x * blockDim.x + threadIdx.x;
    int nth = gridDim.x * blockDim.x;
    float*    WembT  = ws + WS_WEMBT;
    unsigned* WcatT2 = (unsigned*)ws + WS_WCAT2;
    float*    biasc  = ws + WS_BIAS;
    for (int i = tid; i < 256 * 128; i += nth) {
        int k = i >> 7, m = i & 127;
        WembT[i] = W_emb[m * 256 + k];
    }
    for (int i = tid; i < 128 * 512; i += nth) {
        int kp = i >> 9, g = i & 511;
        int k0 = kp * 2, k1 = kp * 2 + 1;
        float w0 = (k0 < 128) ? W_ih[g * 128 + k0] : W_hh[g * 128 + (k0 - 128)];
        float w1 = (k1 < 128) ? W_ih[g * 128 + k1] : W_hh[g * 128 + (k1 - 128)];
        WcatT2[i] = (unsigned)f2bf(w0) | ((unsigned)f2bf(w1) << 16);
    }
    for (int i = tid; i < 512; i += nth) biasc[i] = b_ih[i] + b_hh[i];
}

extern "C" __global__ __launch_bounds__(1024, 1)
void set2vec_main(const float* __restrict__ hidden,
                  const float* __restrict__ input,
                  const float* __restrict__ b_emb,
                  const unsigned char* __restrict__ mask_bytes,
                  const int* __restrict__ Tptr,
                  const float* __restrict__ ws,
                  float* __restrict__ out) {
    __shared__ float mem[2][NN][MPAD];       // 104000 B
    __shared__ float xcat2[2][KD];           // [lstm_in | h] per batch elem
    __shared__ float cbuf[2][MD];
    __shared__ int   mask_is_u8;
    __shared__ __align__(16) char scratch[32768];   // union: xtile | step partials

    float (*xtile)[KD] = (float (*)[KD])scratch;    // [32][256] embed staging
    float* gpart = (float*)scratch;                 // [2][512][2]  8192 B
    float* epart = (float*)(scratch + 8192);        // [2][4][100]  3200 B
    float* rpart = (float*)(scratch + 11392);       // [2][4][128]  4096 B
    float* abuf  = (float*)(scratch + 15488);       // [2][100]      800 B

    const int tid = threadIdx.x;
    const int b0  = blockIdx.x * 2;
    const float*    WembT  = ws + WS_WEMBT;
    const unsigned* WcatT2 = (const unsigned*)ws + WS_WCAT2;
    const float*    biasc  = ws + WS_BIAS;

    // sniff node_mask dtype (bool/u8 vs int32)
    if (tid == 0) {
        int nz = 0;
        for (int i = 0; i < 256; ++i)
            if ((i & 3) && mask_bytes[i]) nz = 1;
        mask_is_u8 = nz;
    }

    // ---- fused embed: mem = cat(hidden,input) @ W_emb^T + b_emb ----
    for (int t0 = 0; t0 < 2 * NN; t0 += 32) {
        int nrows = (2 * NN - t0 < 32) ? (2 * NN - t0) : 32;
        for (int h = 0; h < 2; ++h) {
            int idx = h * 1024 + tid;
            int rr = idx >> 6, q = idx & 63;
            if (rr < nrows) {
                int row = t0 + rr;
                int bb  = row >= NN;
                int n   = row - bb * NN;
                long base = ((long)(b0 + bb) * NN + n) << 7;
                const float* src = (q < 32) ? (hidden + base + (q << 2))
                                            : (input + base + ((q - 32) << 2));
                *(float4*)&xtile[rr][q << 2] = *(const float4*)src;
            }
        }
        __syncthreads();
        {
            int rr = tid >> 5, m0 = (tid & 31) << 2;
            if (rr < nrows) {
                float4 acc = *(const float4*)(b_emb + m0);
                const float* xr = xtile[rr];
                #pragma unroll 4
                for (int k = 0; k < KD; ++k) {
                    float  xv = xr[k];
                    float4 w  = *(const float4*)(WembT + k * MD + m0);
                    acc.x = fmaf(xv, w.x, acc.x); acc.y = fmaf(xv, w.y, acc.y);
                    acc.z = fmaf(xv, w.z, acc.z); acc.w = fmaf(xv, w.w, acc.w);
                }
                int row = t0 + rr, bb = row >= NN, n = row - bb * NN;
                float* dst = &mem[bb][n][m0];
                dst[0] = acc.x; dst[1] = acc.y; dst[2] = acc.z; dst[3] = acc.w;
            }
        }
        __syncthreads();
    }

    // ---- init LSTM state ----
    for (int i = tid; i < 2 * KD; i += 1024) ((float*)xcat2)[i] = 0.0f;
    if (tid < 256) ((float*)cbuf)[tid] = 0.0f;
    __syncthreads();

    const int T = Tptr[0];   // works for i32 or i64-LE scalar

    // ---- per-thread phase constants (hoisted out of the step loop) ----
    const int g  = tid & 511, kh = tid >> 9;           // gates: (gate, k-half)
    const unsigned* Wg = WcatT2 + (kh * 64) * G4 + g;
    const float2* xg0 = (const float2*)&xcat2[0][kh * 128];
    const float2* xg1 = (const float2*)&xcat2[1][kh * 128];
    const float bias0 = (kh == 0) ? biasc[g] : 0.0f;

    const int e_act = tid < 800;                       // energies: (bb, mq, n)
    const int e_bb  = tid / 400;
    const int e_r   = tid - e_bb * 400;
    const int e_mq  = e_r / 100;
    const int e_n   = e_r - e_mq * 100;

    const int r_bb = tid >> 9, r_r = tid & 511;        // read: (bb, nq, m)
    const int r_nq = r_r >> 7, r_m = r_r & 127;

    for (int step = 0; step < T; ++step) {
        // --- gates: each thread = one gate output, half the K range ---
        {
            float a0 = bias0, a1 = bias0;
            #pragma unroll 8
            for (int j = 0; j < 64; ++j) {
                unsigned p   = Wg[j * G4];
                float    wlo = __uint_as_float(p << 16);
                float    whi = __uint_as_float(p & 0xffff0000u);
                float2   v0  = xg0[j], v1 = xg1[j];
                a0 = fmaf(wlo, v0.x, a0); a0 = fmaf(whi, v0.y, a0);
                a1 = fmaf(wlo, v1.x, a1); a1 = fmaf(whi, v1.y, a1);
            }
            gpart[(g << 1) + kh]        = a0;
            gpart[1024 + (g << 1) + kh] = a1;
        }
        __syncthreads();
        // --- LSTM pointwise (i,f,g,o) + K-half combine ---
        if (tid < 256) {
            int bb = tid >> 7, m = tid & 127;
            const float* gp = gpart + bb * 1024;
            float gi = gp[m * 2]         + gp[m * 2 + 1];
            float gf = gp[(128 + m) * 2] + gp[(128 + m) * 2 + 1];
            float gg = gp[(256 + m) * 2] + gp[(256 + m) * 2 + 1];
            float go = gp[(384 + m) * 2] + gp[(384 + m) * 2 + 1];
            float c  = cbuf[bb][m];
            c = sigm(gf) * c + sigm(gi) * tanhf(gg);
            float q = sigm(go) * tanhf(c);
            cbuf[bb][m] = c;
            xcat2[bb][128 + m] = q;
        }
        __syncthreads();
        // --- energies partial: M split into quarters ---
        if (e_act) {
            const float* qv = &xcat2[e_bb][128 + e_mq * 32];
            const float* mr = &mem[e_bb][e_n][e_mq * 32];
            float e = 0.0f;
            #pragma unroll
            for (int i = 0; i < 32; ++i) e = fmaf(qv[i], mr[i], e);
            epart[tid] = e;              // layout [bb][mq][n]
        }
        __syncthreads();
        // --- softmax (combine partials + mask inside) ---
        if (tid < 128) {
            int bb = tid >> 6, l = tid & 63;
            const float* ep = epart + bb * 400;
            long mbase = (long)(b0 + bb) * NN;
            float e0 = ep[l] + ep[100 + l] + ep[200 + l] + ep[300 + l];
            int v0 = mask_is_u8 ? (mask_bytes[mbase + l] != 0)
                                : (((const int*)mask_bytes)[mbase + l] != 0);
            e0 += v0 ? 0.0f : BIG_NEG;
            float e1 = -INFINITY;
            if (l < 36) {
                int n1 = l + 64;
                e1 = ep[n1] + ep[100 + n1] + ep[200 + n1] + ep[300 + n1];
                int v1 = mask_is_u8 ? (mask_bytes[mbase + n1] != 0)
                                    : (((const int*)mask_bytes)[mbase + n1] != 0);
                e1 += v1 ? 0.0f : BIG_NEG;
            }
            float mx = fmaxf(e0, e1);
            for (int off = 32; off; off >>= 1) mx = fmaxf(mx, __shfl_xor(mx, off, 64));
            float p0 = __expf(e0 - mx);
            float p1 = (l < 36) ? __expf(e1 - mx) : 0.0f;
            float s = p0 + p1;
            for (int off = 32; off; off >>= 1) s += __shfl_xor(s, off, 64);
            float inv = 1.0f / s;
            abuf[bb * 100 + l] = p0 * inv;
            if (l < 36) abuf[bb * 100 + l + 64] = p1 * inv;
        }
        __syncthreads();
        // --- read partial: N split into quarters ---
        {
            const float* ar = abuf + r_bb * 100 + r_nq * 25;
            const float* mr = &mem[r_bb][r_nq * 25][r_m];
            float r = 0.0f;
            #pragma unroll
            for (int j = 0; j < 25; ++j) r = fmaf(ar[j], mr[j * MPAD], r);
            rpart[tid] = r;              // layout [bb][nq][m]
        }
        __syncthreads();
        // --- read combine -> lstm_in for next step ---
        if (tid < 256) {
            int bb = tid >> 7, m = tid & 127;
            const float* rp = rpart + bb * 512;
            xcat2[bb][m] = rp[m] + rp[128 + m] + rp[256 + m] + rp[384 + m];
        }
        __syncthreads();
    }

    // ---- output: [q | read] ----
    if (tid < 512) {
        int bb = tid >> 8, j = tid & 255;
        float v = (j < 128) ? xcat2[bb][128 + j] : xcat2[bb][j - 128];
        out[((long)(b0 + bb) << 8) + j] = v;
    }
}

extern "C" void kernel_launch(void* const* d_in, const int* in_sizes, int n_in,
                              void* d_out, int out_size, void* d_ws, size_t ws_size,
                              hipStream_t stream) {
    const float* hidden = (const float*)d_in[0];
    const float* input  = (const float*)d_in[1];
    const float* W_emb  = (const float*)d_in[2];
    const float* b_emb  = (const float*)d_in[3];
    const float* W_ih   = (const float*)d_in[4];
    const float* b_ih   = (const float*)d_in[5];
    const float* W_hh   = (const float*)d_in[6];
    const float* b_hh   = (const float*)d_in[7];
    const unsigned char* mask = (const unsigned char*)d_in[8];
    const int*  Tptr    = (const int*)d_in[9];
    float* ws  = (float*)d_ws;
    float* outp = (float*)d_out;

    hipLaunchKernelGGL(prep_kernel, dim3(128), dim3(256), 0, stream,
                       W_emb, W_ih, b_ih, W_hh, b_hh, ws);
    hipLaunchKernelGGL(set2vec_main, dim3(1024), dim3(1024), 0, stream,
                       hidden, input, b_emb, mask, Tptr, ws, outp);
}